// Round 5
// baseline (58.156 us; speedup 1.0000x reference)
//
#include <hip/hip_runtime.h>
#include <math.h>

#define NB 16
#define NN 64
#define NF 64
#define NH 4
#define NR 50
#define NC 256

typedef __attribute__((ext_vector_type(8))) short short8;
typedef __attribute__((ext_vector_type(4))) float f32x4;

// ---- wpack short offsets (fragment-major bf16 weight packs) ----
#define WS_WE1R 0          // 512 entries  (K=64 rbf part of W_e1)
#define WS_WE2  4096       // 512          (K=64)
#define WS_WX   8192       // 8192         (K=256, N=256)
#define WS_PO1  73728      // 2048         (K=256, N=64)
#define WS_NO1  90112      // 3072         (K=384, N=64)
#define WS_PO2  114688     // 512
#define WS_NO2  118784     // 512
#define WS_VE1  122880     // 512
// ---- float offsets in ws ----
#define MID_F   65536                  // mid_T[128][1024]
#define E1_F    (MID_F + 131072)       // e1[node][128]
#define HAGG_F  (E1_F + 131072)        // hagg[1024][256]
#define COMB_F  (HAGG_F + 262144)      // comb[1024][768]

__device__ __forceinline__ float siluf(float x) { return x / (1.f + __expf(-x)); }
__device__ __forceinline__ float tanhfast(float x) { return 1.f - 2.f / (__expf(2.f * x) + 1.f); }

__device__ __forceinline__ short f2bfs(float f) {
    __bf16 b = (__bf16)f;
    union { __bf16 b; short s; } u; u.b = b; return u.s;
}
__device__ __forceinline__ float bf1(ushort u) {
    union { unsigned u; float f; } c; c.u = ((unsigned)u) << 16; return c.f;
}
__device__ __forceinline__ float bflo(unsigned u) {
    union { unsigned u; float f; } c; c.u = u << 16; return c.f;
}
__device__ __forceinline__ float bfhi(unsigned u) {
    union { unsigned u; float f; } c; c.u = u & 0xFFFF0000u; return c.f;
}

__device__ __forceinline__ float wave_max(float v) {
#pragma unroll
    for (int s = 32; s >= 1; s >>= 1) v = fmaxf(v, __shfl_xor(v, s));
    return v;
}
__device__ __forceinline__ float wave_sum(float v) {
#pragma unroll
    for (int s = 32; s >= 1; s >>= 1) v += __shfl_xor(v, s);
    return v;
}

// =============== prep: weight packs + per-node precomputes ===============
__global__ __launch_bounds__(256)
void prep_kernel(const float* __restrict__ W_e1, const float* __restrict__ b_e1,
                 const float* __restrict__ W_e2, const float* __restrict__ W_xmix,
                 const float* __restrict__ W_post1, const float* __restrict__ W_node1,
                 const float* __restrict__ W_post2, const float* __restrict__ W_node2,
                 const float* __restrict__ W_vel1,
                 const float* __restrict__ h, const float* __restrict__ W_in,
                 const float* __restrict__ b_in,
                 short* __restrict__ wpack, float* __restrict__ mid_T, float* __restrict__ e1)
{
    int blk = blockIdx.x, t = threadIdx.x;
    if (blk < 62) {
        int s = blk * 256 + t;   // 0..15871
        short8 val;
        if (s < 512) {               // W_e1 rbf part: K=64 (50 rbf + d + pad)
            int cl = s & 15, g = (s >> 4) & 3, q = s >> 6;
            int ks = q & 1, nt = q >> 1;
            int c = nt * 16 + cl, k0 = 32 * ks + 8 * g;
#pragma unroll
            for (int i = 0; i < 8; i++) {
                int kr = k0 + i;
                float f = (kr < 50) ? W_e1[(128 + kr) * NF + c] : (kr == 50 ? W_e1[178 * NF + c] : 0.f);
                val[i] = f2bfs(f);
            }
            *(short8*)(&wpack[WS_WE1R + s * 8]) = val;
        } else if (s < 1024) {        // W_e2 K=64
            int u = s - 512;
            int cl = u & 15, g = (u >> 4) & 3, q = u >> 6;
            int ks = q & 1, nt = q >> 1;
            int c = nt * 16 + cl, k0 = 32 * ks + 8 * g;
#pragma unroll
            for (int i = 0; i < 8; i++) val[i] = f2bfs(W_e2[(k0 + i) * NF + c]);
            *(short8*)(&wpack[WS_WE2 + u * 8]) = val;
        } else if (s < 9216) {        // W_xmix K=256 N=256
            int u = s - 1024;
            int cl = u & 15, g = (u >> 4) & 3, q = u >> 6;
            int ks = q & 7, wn = q >> 3;
            int c = (wn >> 2) * 64 + (wn & 3) * 16 + cl, k0 = 32 * ks + 8 * g;
#pragma unroll
            for (int i = 0; i < 8; i++) val[i] = f2bfs(W_xmix[(k0 + i) * NC + c]);
            *(short8*)(&wpack[WS_WX + u * 8]) = val;
        } else if (s < 11264) {       // W_post1 K=256 N=64
            int u = s - 9216;
            int cl = u & 15, g = (u >> 4) & 3, q = u >> 6;
            int ks = q & 7, nt = q >> 3;
            int c = nt * 16 + cl, k0 = 32 * ks + 8 * g;
#pragma unroll
            for (int i = 0; i < 8; i++) val[i] = f2bfs(W_post1[(k0 + i) * NF + c]);
            *(short8*)(&wpack[WS_PO1 + u * 8]) = val;
        } else if (s < 14336) {       // W_node1 K=384 N=64
            int u = s - 11264;
            int cl = u & 15, g = (u >> 4) & 3, q = u >> 6;
            int ks = q % 12, nt = q / 12;
            int c = nt * 16 + cl, k0 = 32 * ks + 8 * g;
#pragma unroll
            for (int i = 0; i < 8; i++) val[i] = f2bfs(W_node1[(k0 + i) * NF + c]);
            *(short8*)(&wpack[WS_NO1 + u * 8]) = val;
        } else if (s < 14848) {       // W_post2 K=64
            int u = s - 14336;
            int cl = u & 15, g = (u >> 4) & 3, q = u >> 6;
            int ks = q & 1, nt = q >> 1;
            int c = nt * 16 + cl, k0 = 32 * ks + 8 * g;
#pragma unroll
            for (int i = 0; i < 8; i++) val[i] = f2bfs(W_post2[(k0 + i) * NF + c]);
            *(short8*)(&wpack[WS_PO2 + u * 8]) = val;
        } else if (s < 15360) {       // W_node2 K=64
            int u = s - 14848;
            int cl = u & 15, g = (u >> 4) & 3, q = u >> 6;
            int ks = q & 1, nt = q >> 1;
            int c = nt * 16 + cl, k0 = 32 * ks + 8 * g;
#pragma unroll
            for (int i = 0; i < 8; i++) val[i] = f2bfs(W_node2[(k0 + i) * NF + c]);
            *(short8*)(&wpack[WS_NO2 + u * 8]) = val;
        } else {                      // W_vel1 K=64
            int u = s - 15360;
            int cl = u & 15, g = (u >> 4) & 3, q = u >> 6;
            int ks = q & 1, nt = q >> 1;
            int c = nt * 16 + cl, k0 = 32 * ks + 8 * g;
#pragma unroll
            for (int i = 0; i < 8; i++) val[i] = f2bfs(W_vel1[(k0 + i) * NF + c]);
            *(short8*)(&wpack[WS_VE1 + u * 8]) = val;
        }
    } else {
        int node = blk - 62;
        __shared__ float s_hn[64];
        if (t < 64) s_hn[t] = h[node * NF + t];
        __syncthreads();
        if (t < 64) {                    // E1j
            float acc = 0.f;
#pragma unroll 8
            for (int k = 0; k < 64; k++) acc += s_hn[k] * W_e1[k * NF + t];
            e1[node * 128 + t] = acc;
        } else if (t < 128) {            // E1i + b_e1
            int f = t - 64;
            float acc = b_e1[f];
#pragma unroll 8
            for (int k = 0; k < 64; k++) acc += s_hn[k] * W_e1[(64 + k) * NF + f];
            e1[node * 128 + 64 + f] = acc;
        } else if (t < 178) {            // midj -> transposed
            int r = t - 128;
            float acc = 0.f;
#pragma unroll 8
            for (int k = 0; k < 64; k++) acc += s_hn[k] * W_in[k * NR + r];
            mid_T[r * 1024 + node] = acc;
        } else if (t >= 192 && t < 242) { // midi (+b_in) -> transposed
            int r = t - 192;
            float acc = b_in[r];
#pragma unroll 8
            for (int k = 0; k < 64; k++) acc += s_hn[k] * W_in[(64 + k) * NR + r];
            mid_T[(64 + r) * 1024 + node] = acc;
        }
    }
}

// =============== edge: one block per (b,i) ===============
__global__ __launch_bounds__(256)
void sake_edge_kernel(
    const float* __restrict__ x,
    const float* __restrict__ mid_T, const float* __restrict__ e1,
    const float* __restrict__ rbf_means, const float* __restrict__ rbf_betas,
    const float* __restrict__ b_e2,
    const float* __restrict__ W_sem, const float* __restrict__ b_sem,
    const float* __restrict__ log_gamma,
    const short* __restrict__ wpack,
    float* __restrict__ hagg_g, float* __restrict__ comb_g)
{
    const int bi = blockIdx.x;
    const int b  = bi >> 6;
    const int i  = bi & 63;
    const int t  = threadIdx.x;
    const int w  = t >> 6, l = t & 63, lr = l & 15, lg = l >> 4;

    __shared__ __align__(16) short s_A[16 * 64 * 8];   // 16 KiB fragment-major A
    __shared__ __align__(16) short s_he[64 * 72];      // 9 KiB h_e bf16, stride 72 (16B-aligned rows)
    __shared__ float s_xhat[256];
    __shared__ float s_att[256];
    __shared__ float s_wsem[256];
    __shared__ float s_midi[52];

    const short8* A8  = (const short8*)s_A;
    short8*       A8w = (short8*)s_A;
    const short8* We1p = (const short8*)(wpack + WS_WE1R);
    const short8* We2p = (const short8*)(wpack + WS_WE2);
    const short8* Wxp  = (const short8*)(wpack + WS_WX);

    // ---------- P0 ----------
    s_wsem[t] = W_sem[t];
    if (t < 50) s_midi[t] = mid_T[(64 + t) * 1024 + b * 64 + i];
    if (t < 64) {
        int j = t;
        float dx = x[(b * NN + j) * 3 + 0] - x[(b * NN + i) * 3 + 0];
        float dy = x[(b * NN + j) * 3 + 1] - x[(b * NN + i) * 3 + 1];
        float dz = x[(b * NN + j) * 3 + 2] - x[(b * NN + i) * 3 + 2];
        float d2 = dx * dx + dy * dy + dz * dz;
        float d  = sqrtf(fmaxf(d2, 0.f) + 1e-5f);
        float inv = 1.f / (d + 1e-5f);
        s_xhat[j * 4 + 0] = dx * inv;
        s_xhat[j * 4 + 1] = dy * inv;
        s_xhat[j * 4 + 2] = dz * inv;
        s_xhat[j * 4 + 3] = d;
    }
    __syncthreads();

    // ---------- P1: rbf A slots 0..7 (coalesced mid_T loads) ----------
    {
        int j = t & 63, p = t >> 6;
        float d = s_xhat[j * 4 + 3];
        float cut = 0.5f * (__cosf(d * 0.6283185307179586f) + 1.f) * (d < 5.f ? 1.f : 0.f);
        float emd = __expf(-d);
        const float* mcol = mid_T + b * 64 + j;
#pragma unroll
        for (int q = 0; q < 2; q++) {
            int sl = 2 * p + q;
            short8 val;
#pragma unroll
            for (int e = 0; e < 8; e++) {
                int r = sl * 8 + e;
                float o;
                if (r < 50) {
                    float m = mcol[r * 1024] + s_midi[r];
                    float df = emd - rbf_means[r];
                    o = cut * __expf(-rbf_betas[r] * df * df) * m;
                } else if (r == 50) o = d;
                else o = 0.f;
                val[e] = f2bfs(o);
            }
            A8w[sl * 64 + j] = val;
        }
    }
    __syncthreads();

    // ---------- P2 (MFMA K=64, C-init = E1j+E1i): u -> slots 8..15 ----------
    {
        int f = w * 16 + lr;
        const float* e1b = e1 + (size_t)b * 64 * 128;
        float e1i_v = e1b[i * 128 + 64 + f];
        f32x4 acc[4];
#pragma unroll
        for (int jt = 0; jt < 4; jt++)
#pragma unroll
            for (int r = 0; r < 4; r++) {
                int j = jt * 16 + lg * 4 + r;
                acc[jt][r] = e1b[j * 128 + f] + e1i_v;
            }
#pragma unroll
        for (int ks = 0; ks < 2; ks++) {
            short8 bb = We1p[(w * 2 + ks) * 64 + l];
#pragma unroll
            for (int jt = 0; jt < 4; jt++) {
                short8 aa = A8[(ks * 4 + lg) * 64 + jt * 16 + lr];
                acc[jt] = __builtin_amdgcn_mfma_f32_16x16x32_bf16(aa, bb, acc[jt], 0, 0, 0);
            }
        }
        // write u to slots 8..15 (no overwrite of rbf slots -> no extra barrier)
#pragma unroll
        for (int jt = 0; jt < 4; jt++)
#pragma unroll
            for (int r = 0; r < 4; r++) {
                int j = jt * 16 + lg * 4 + r;
                s_A[(((f >> 3) + 8) * 64 + j) * 8 + (f & 7)] = f2bfs(siluf(acc[jt][r]));
            }
        __syncthreads();
    }

    // ---------- P3 (MFMA): h_e = u @ W_e2 + b_e2 -> s_he ----------
    {
        f32x4 acc[4];
#pragma unroll
        for (int jt = 0; jt < 4; jt++) { acc[jt][0] = 0.f; acc[jt][1] = 0.f; acc[jt][2] = 0.f; acc[jt][3] = 0.f; }
#pragma unroll
        for (int ks = 0; ks < 2; ks++) {
            short8 bb = We2p[(w * 2 + ks) * 64 + l];
#pragma unroll
            for (int jt = 0; jt < 4; jt++) {
                short8 aa = A8[((8 + ks * 4 + lg)) * 64 + jt * 16 + lr];
                acc[jt] = __builtin_amdgcn_mfma_f32_16x16x32_bf16(aa, bb, acc[jt], 0, 0, 0);
            }
        }
        float be2 = b_e2[w * 16 + lr];
        int f = w * 16 + lr;
#pragma unroll
        for (int jt = 0; jt < 4; jt++)
#pragma unroll
            for (int r = 0; r < 4; r++) {
                int j = jt * 16 + lg * 4 + r;
                s_he[j * 72 + f] = f2bfs(acc[jt][r] + be2);
            }
        __syncthreads();
    }

    // ---------- P4: sem/euc softmax over j (b128 h_e reads) ----------
    {
        int hh = w, j = l;
        const short8* hrow = (const short8*)(s_he + j * 72);
        float acc = b_sem[hh];
#pragma unroll
        for (int q = 0; q < 8; q++) {
            short8 hv = hrow[q];
#pragma unroll
            for (int e = 0; e < 8; e++)
                acc += bf1((ushort)hv[e]) * s_wsem[(q * 8 + e) * 4 + hh];
        }
        float cel = fmaxf(acc, 0.f) + fminf(0.f, 2.f * (__expf(0.5f * acc) - 1.f));
        float diag = (j == i) ? 1e5f : 0.f;
        float slog = cel - diag;
        float m1 = wave_max(slog);
        float e1v = __expf(slog - m1);
        float sem = e1v / wave_sum(e1v);
        float gam = __expf(log_gamma[hh]);
        float elog = -(s_xhat[j * 4 + 3] + diag) * gam;
        float m2 = wave_max(elog);
        float e2 = __expf(elog - m2);
        float euc = e2 / wave_sum(e2);
        float a = sem * euc;
        a = a / wave_sum(a);
        s_att[j * 4 + hh] = a;
    }
    __syncthreads();

    // ---------- P5: h_agg (u32 reads, split j across lane pairs) ----------
    {
        int f2 = t >> 3, hh = (t >> 1) & 3, jh = t & 1;
        float a0 = 0.f, a1 = 0.f;
#pragma unroll 8
        for (int jj = 0; jj < 32; jj++) {
            int j = jh * 32 + jj;
            float at = s_att[j * 4 + hh];
            unsigned u = *(const unsigned*)(s_he + j * 72 + 2 * f2);
            a0 += bflo(u) * at;
            a1 += bfhi(u) * at;
        }
        a0 += __shfl_xor(a0, 1);
        a1 += __shfl_xor(a1, 1);
        if (!jh) {
            hagg_g[bi * 256 + (2 * f2) * 4 + hh]     = a0;
            hagg_g[bi * 256 + (2 * f2 + 1) * 4 + hh] = a1;
        }
    }

    // ---------- P6: xmix GEMM, two K-halves ----------
    f32x4 acc[4][4];
#pragma unroll
    for (int jt = 0; jt < 4; jt++)
#pragma unroll
        for (int nt = 0; nt < 4; nt++) { acc[jt][nt][0] = 0.f; acc[jt][nt][1] = 0.f; acc[jt][nt][2] = 0.f; acc[jt][nt][3] = 0.f; }

    for (int half = 0; half < 2; half++) {
        {   // build hea slots 0..15: one b128 read covers this thread's 4 slots
            int j = t & 63, kc = t >> 6;
            float a0 = s_att[j * 4 + 0], a1 = s_att[j * 4 + 1];
            float a2 = s_att[j * 4 + 2], a3 = s_att[j * 4 + 3];
            short8 hv = *(const short8*)(s_he + j * 72 + (half * 32 + kc * 8));
#pragma unroll
            for (int s = 0; s < 4; s++) {
                int sl = kc * 4 + s;
                float h0 = bf1((ushort)hv[2 * s]), h1 = bf1((ushort)hv[2 * s + 1]);
                short8 val;
                val[0] = f2bfs(h0 * a0); val[1] = f2bfs(h0 * a1);
                val[2] = f2bfs(h0 * a2); val[3] = f2bfs(h0 * a3);
                val[4] = f2bfs(h1 * a0); val[5] = f2bfs(h1 * a1);
                val[6] = f2bfs(h1 * a2); val[7] = f2bfs(h1 * a3);
                A8w[sl * 64 + j] = val;
            }
        }
        __syncthreads();
#pragma unroll
        for (int ks = 0; ks < 4; ks++) {
            short8 aa[4], bb[4];
#pragma unroll
            for (int jt = 0; jt < 4; jt++) aa[jt] = A8[(ks * 4 + lg) * 64 + jt * 16 + lr];
#pragma unroll
            for (int nt = 0; nt < 4; nt++) bb[nt] = Wxp[((w * 4 + nt) * 8 + half * 4 + ks) * 64 + l];
#pragma unroll
            for (int jt = 0; jt < 4; jt++)
#pragma unroll
                for (int nt = 0; nt < 4; nt++)
                    acc[jt][nt] = __builtin_amdgcn_mfma_f32_16x16x32_bf16(aa[jt], bb[nt], acc[jt][nt], 0, 0, 0);
        }
        __syncthreads();
    }

    // epilogue: tanh, x_hat-weight, reduce over j -> comb (mean)
    {
#pragma unroll
        for (int nt = 0; nt < 4; nt++) {
            float p0 = 0.f, p1 = 0.f, p2 = 0.f;
#pragma unroll
            for (int jt = 0; jt < 4; jt++)
#pragma unroll
                for (int r = 0; r < 4; r++) {
                    int j = jt * 16 + lg * 4 + r;
                    float th = tanhfast(acc[jt][nt][r]);
                    p0 += s_xhat[j * 4 + 0] * th;
                    p1 += s_xhat[j * 4 + 1] * th;
                    p2 += s_xhat[j * 4 + 2] * th;
                }
            p0 += __shfl_xor(p0, 16); p0 += __shfl_xor(p0, 32);
            p1 += __shfl_xor(p1, 16); p1 += __shfl_xor(p1, 32);
            p2 += __shfl_xor(p2, 16); p2 += __shfl_xor(p2, 32);
            if (lg == 0) {
                int c = w * 64 + nt * 16 + lr;
                float* cg = comb_g + bi * 768 + c * 3;
                cg[0] = p0 * (1.f / 64.f);
                cg[1] = p1 * (1.f / 64.f);
                cg[2] = p2 * (1.f / 64.f);
            }
        }
    }
}

// =============== tail: 64 blocks x 16-node tiles, MFMA MLP chain ===============
__global__ __launch_bounds__(256)
void sake_tail_kernel(
    const float* __restrict__ h, const float* __restrict__ x, const float* __restrict__ v,
    const float* __restrict__ hagg_g, const float* __restrict__ comb_g,
    const float* __restrict__ b_post1, const float* __restrict__ b_post2,
    const float* __restrict__ b_node1, const float* __restrict__ b_node2,
    const float* __restrict__ b_vel1,
    const float* __restrict__ W_vel2, const float* __restrict__ W_vmix,
    const short* __restrict__ wpack,
    float* __restrict__ out_h, float* __restrict__ out_x, float* __restrict__ out_v)
{
    const int g0 = blockIdx.x * 16;            // first node of tile
    const int t = threadIdx.x;
    const int w = t >> 6, l = t & 63, lr = l & 15, lg = l >> 4;

    // A slots: 0..31 hcp | 32..79 node1 [h|hagg|hcomb] | 80..87 post2 | 0..7 node2 | 8..15 vel1
    __shared__ __align__(16) short s_Aa[88 * 16 * 8];   // 22 KiB
    __shared__ float s_wv[256];
    __shared__ float s_wv2[64];
    __shared__ float s_red[4][16];

    const short8* A8  = (const short8*)s_Aa;
    const short8* PO1p = (const short8*)(wpack + WS_PO1);
    const short8* NO1p = (const short8*)(wpack + WS_NO1);
    const short8* PO2p = (const short8*)(wpack + WS_PO2);
    const short8* NO2p = (const short8*)(wpack + WS_NO2);
    const short8* VE1p = (const short8*)(wpack + WS_VE1);

    // ---- ph1: stage hcp (slots 0..31), h (32..39), hagg (40..71), W_vmix, W_vel2 ----
    {
        s_wv[t] = W_vmix[t];
        if (t < 64) s_wv2[t] = W_vel2[t];
        int n = t & 15, c0 = (t >> 4) * 16;
        const float* cg = comb_g + (g0 + n) * 768;
        const float* ha = hagg_g + (g0 + n) * 256;
#pragma unroll
        for (int cc = 0; cc < 16; cc++) {
            int c = c0 + cc;
            float v0 = cg[c * 3 + 0], v1 = cg[c * 3 + 1], v2 = cg[c * 3 + 2];
            float hcp = v0 * v0 + v1 * v1 + v2 * v2;
            s_Aa[((c >> 3) * 16 + n) * 8 + (c & 7)] = f2bfs(hcp);
            s_Aa[((40 + (c >> 3)) * 16 + n) * 8 + (c & 7)] = f2bfs(ha[c]);
        }
        int f0 = (t >> 4) * 4;
#pragma unroll
        for (int ff = 0; ff < 4; ff++) {
            int f = f0 + ff;
            s_Aa[((32 + (f >> 3)) * 16 + n) * 8 + (f & 7)] = f2bfs(h[(g0 + n) * 64 + f]);
        }
    }
    __syncthreads();

    // ---- ph2: post1 (K=256) -> silu -> post2-A slots 80..87 ----
    {
        f32x4 acc = {0.f, 0.f, 0.f, 0.f};
#pragma unroll
        for (int ks = 0; ks < 8; ks++) {
            short8 aa = A8[(ks * 4 + lg) * 16 + lr];
            short8 bb = PO1p[((w * 8 + ks) * 4 + lg) * 16 + lr];
            acc = __builtin_amdgcn_mfma_f32_16x16x32_bf16(aa, bb, acc, 0, 0, 0);
        }
        int f = w * 16 + lr;
        float bp = b_post1[f];
        __syncthreads();   // hcp reads complete before any later overwrite patterns
#pragma unroll
        for (int r = 0; r < 4; r++) {
            int n = lg * 4 + r;
            s_Aa[((80 + (f >> 3)) * 16 + n) * 8 + (f & 7)] = f2bfs(siluf(acc[r] + bp));
        }
        __syncthreads();
    }

    // ---- ph3: post2 (K=64) -> silu -> hcomb slots 72..79 ----
    {
        f32x4 acc = {0.f, 0.f, 0.f, 0.f};
#pragma unroll
        for (int ks = 0; ks < 2; ks++) {
            short8 aa = A8[((80 + ks * 4 + lg)) * 16 + lr];
            short8 bb = PO2p[((w * 2 + ks) * 4 + lg) * 16 + lr];
            acc = __builtin_amdgcn_mfma_f32_16x16x32_bf16(aa, bb, acc, 0, 0, 0);
        }
        int f = w * 16 + lr;
        float bp = b_post2[f];
#pragma unroll
        for (int r = 0; r < 4; r++) {
            int n = lg * 4 + r;
            s_Aa[((72 + (f >> 3)) * 16 + n) * 8 + (f & 7)] = f2bfs(siluf(acc[r] + bp));
        }
        __syncthreads();
    }

    // ---- ph4: node1 (K=384, slots 32..79) -> silu -> node2-A slots 0..7 ----
    {
        f32x4 acc = {0.f, 0.f, 0.f, 0.f};
#pragma unroll
        for (int ks = 0; ks < 12; ks++) {
            short8 aa = A8[((32 + ks * 4 + lg)) * 16 + lr];
            short8 bb = NO1p[((w * 12 + ks) * 4 + lg) * 16 + lr];
            acc = __builtin_amdgcn_mfma_f32_16x16x32_bf16(aa, bb, acc, 0, 0, 0);
        }
        int f = w * 16 + lr;
        float bp = b_node1[f];
#pragma unroll
        for (int r = 0; r < 4; r++) {
            int n = lg * 4 + r;
            s_Aa[((f >> 3) * 16 + n) * 8 + (f & 7)] = f2bfs(siluf(acc[r] + bp));
        }
        __syncthreads();
    }

    // ---- ph5: node2 (K=64) + residual -> out_h, vel1-A slots 8..15 ----
    {
        f32x4 acc = {0.f, 0.f, 0.f, 0.f};
#pragma unroll
        for (int ks = 0; ks < 2; ks++) {
            short8 aa = A8[(ks * 4 + lg) * 16 + lr];
            short8 bb = NO2p[((w * 2 + ks) * 4 + lg) * 16 + lr];
            acc = __builtin_amdgcn_mfma_f32_16x16x32_bf16(aa, bb, acc, 0, 0, 0);
        }
        int f = w * 16 + lr;
        float bp = b_node2[f];
#pragma unroll
        for (int r = 0; r < 4; r++) {
            int n = lg * 4 + r;
            float ho = h[(g0 + n) * 64 + f] + siluf(acc[r] + bp);
            out_h[(g0 + n) * 64 + f] = ho;
            s_Aa[((8 + (f >> 3)) * 16 + n) * 8 + (f & 7)] = f2bfs(ho);
        }
        __syncthreads();
    }

    // ---- ph6: vel1 (K=64) -> silu -> gate partials ----
    {
        f32x4 acc = {0.f, 0.f, 0.f, 0.f};
#pragma unroll
        for (int ks = 0; ks < 2; ks++) {
            short8 aa = A8[((8 + ks * 4 + lg)) * 16 + lr];
            short8 bb = VE1p[((w * 2 + ks) * 4 + lg) * 16 + lr];
            acc = __builtin_amdgcn_mfma_f32_16x16x32_bf16(aa, bb, acc, 0, 0, 0);
        }
        int f = w * 16 + lr;
        float bp = b_vel1[f];
        float wv2 = s_wv2[f];
#pragma unroll
        for (int r = 0; r < 4; r++) {
            float p = siluf(acc[r] + bp) * wv2;
            p += __shfl_xor(p, 1); p += __shfl_xor(p, 2);
            p += __shfl_xor(p, 4); p += __shfl_xor(p, 8);
            if (lr == 0) s_red[w][lg * 4 + r] = p;   // partial over this wave's 16 f
        }
        __syncthreads();
    }

    // ---- ph7: gate + delta_v + v/x outputs ----
    {
        int n = t >> 4, q = t & 15;
        float p0 = 0.f, p1 = 0.f, p2 = 0.f;
        const float* cg = comb_g + (g0 + n) * 768;
#pragma unroll
        for (int cc = 0; cc < 16; cc++) {
            int c = q * 16 + cc;
            float wv = s_wv[c];
            p0 += cg[c * 3 + 0] * wv;
            p1 += cg[c * 3 + 1] * wv;
            p2 += cg[c * 3 + 2] * wv;
        }
        p0 += __shfl_xor(p0, 1); p0 += __shfl_xor(p0, 2); p0 += __shfl_xor(p0, 4); p0 += __shfl_xor(p0, 8);
        p1 += __shfl_xor(p1, 1); p1 += __shfl_xor(p1, 2); p1 += __shfl_xor(p1, 4); p1 += __shfl_xor(p1, 8);
        p2 += __shfl_xor(p2, 1); p2 += __shfl_xor(p2, 2); p2 += __shfl_xor(p2, 4); p2 += __shfl_xor(p2, 8);
        if (q == 0) {
            float g = s_red[0][n] + s_red[1][n] + s_red[2][n] + s_red[3][n];
            g = 2.f / (1.f + __expf(-g));
            float dv0 = p0 + g * v[(g0 + n) * 3 + 0];
            float dv1 = p1 + g * v[(g0 + n) * 3 + 1];
            float dv2 = p2 + g * v[(g0 + n) * 3 + 2];
            out_v[(g0 + n) * 3 + 0] = dv0;
            out_v[(g0 + n) * 3 + 1] = dv1;
            out_v[(g0 + n) * 3 + 2] = dv2;
            out_x[(g0 + n) * 3 + 0] = x[(g0 + n) * 3 + 0] + dv0;
            out_x[(g0 + n) * 3 + 1] = x[(g0 + n) * 3 + 1] + dv1;
            out_x[(g0 + n) * 3 + 2] = x[(g0 + n) * 3 + 2] + dv2;
        }
    }
}

extern "C" void kernel_launch(void* const* d_in, const int* in_sizes, int n_in,
                              void* d_out, int out_size, void* d_ws, size_t ws_size,
                              hipStream_t stream) {
    const float* h        = (const float*)d_in[0];
    const float* x        = (const float*)d_in[1];
    const float* v        = (const float*)d_in[2];
    const float* W_in     = (const float*)d_in[3];
    const float* b_in     = (const float*)d_in[4];
    const float* rbf_m    = (const float*)d_in[5];
    const float* rbf_b    = (const float*)d_in[6];
    const float* W_e1     = (const float*)d_in[7];
    const float* b_e1     = (const float*)d_in[8];
    const float* W_e2     = (const float*)d_in[9];
    const float* b_e2     = (const float*)d_in[10];
    const float* W_sem    = (const float*)d_in[11];
    const float* b_sem    = (const float*)d_in[12];
    const float* log_g    = (const float*)d_in[13];
    const float* W_xmix   = (const float*)d_in[14];
    const float* W_post1  = (const float*)d_in[15];
    const float* b_post1  = (const float*)d_in[16];
    const float* W_post2  = (const float*)d_in[17];
    const float* b_post2  = (const float*)d_in[18];
    const float* W_node1  = (const float*)d_in[19];
    const float* b_node1  = (const float*)d_in[20];
    const float* W_node2  = (const float*)d_in[21];
    const float* b_node2  = (const float*)d_in[22];
    const float* W_vel1   = (const float*)d_in[23];
    const float* b_vel1   = (const float*)d_in[24];
    const float* W_vel2   = (const float*)d_in[25];
    const float* W_vmix   = (const float*)d_in[26];

    float* out   = (float*)d_out;
    float* out_h = out;
    float* out_x = out + NB * NN * NF;
    float* out_v = out + NB * NN * NF + NB * NN * 3;

    short* wpack = (short*)d_ws;
    float* wsf   = (float*)d_ws;
    float* mid_T = wsf + MID_F;
    float* e1    = wsf + E1_F;
    float* hagg  = wsf + HAGG_F;
    float* comb  = wsf + COMB_F;

    prep_kernel<<<62 + 1024, 256, 0, stream>>>(
        W_e1, b_e1, W_e2, W_xmix, W_post1, W_node1, W_post2, W_node2, W_vel1,
        h, W_in, b_in, wpack, mid_T, e1);

    sake_edge_kernel<<<NB * NN, 256, 0, stream>>>(
        x, mid_T, e1, rbf_m, rbf_b, b_e2, W_sem, b_sem, log_g,
        wpack, hagg, comb);

    sake_tail_kernel<<<64, 256, 0, stream>>>(
        h, x, v, hagg, comb,
        b_post1, b_post2, b_node1, b_node2, b_vel1,
        W_vel2, W_vmix, wpack, out_h, out_x, out_v);
}